// Round 4
// baseline (121.047 us; speedup 1.0000x reference)
//
#include <hip/hip_runtime.h>

typedef float f32x2 __attribute__((ext_vector_type(2)));
typedef float f32x4 __attribute__((ext_vector_type(4)));

#define HH 128
#define WW 192
#define HO 256
#define WO 384
#define NINST 256
#define OTY 64          // output rows per block
#define LTYMAX 34       // low-res rows staged
#define LPAD 196        // tile row pitch (784B: 16B aligned, offsets banks by 4)
#define STRIPS 24       // 192/8 strips per low-res row
#define NT 384          // block size (6 waves): thread == output column in upsample

static __device__ __forceinline__ f32x2 splat2(float v) { f32x2 r; r.x = v; r.y = v; return r; }

static __device__ __forceinline__ f32x2 pkfma(f32x2 a, float w, f32x2 c) {
#if __has_builtin(__builtin_elementwise_fma)
    return __builtin_elementwise_fma(a, splat2(w), c);
#else
    f32x2 r; r.x = fmaf(a.x, w, c.x); r.y = fmaf(a.y, w, c.y); return r;
#endif
}

static __device__ __forceinline__ f32x2 relu2(f32x2 a) {
#if __has_builtin(__builtin_elementwise_max)
    return __builtin_elementwise_max(a, splat2(0.0f));
#else
    f32x2 r; r.x = fmaxf(a.x, 0.0f); r.y = fmaxf(a.y, 0.0f); return r;
#endif
}

__global__ __launch_bounds__(NT) void dynmask_fused(
    const float* __restrict__ feats,    // (2, 8, 128, 192)
    const float* __restrict__ params,   // (256, 169)
    const float* __restrict__ locs,     // (256, 2)  [x, y]
    const float* __restrict__ soi,      // (256,)
    const int*   __restrict__ im_inds,  // (256,)
    const int*   __restrict__ stride_p, // (1,)
    float* __restrict__ out)            // (256, 1, 256, 384)
{
    const int n   = blockIdx.y;
    const int t   = threadIdx.x;
    const int oy0 = blockIdx.x * OTY;

    __shared__ float tile[LTYMAX][LPAD];   // 26656 B

    const float sy = 127.0f / 255.0f;
    const float sx = 191.0f / 383.0f;

    const int ly0    = (int)((float)oy0 * sy);
    int lylast       = (int)((float)(oy0 + OTY - 1) * sy) + 1;
    if (lylast > HH - 1) lylast = HH - 1;
    const int lcount = lylast - ly0 + 1;            // 33 or 34

    // wave-uniform -> SGPRs / s_loads
    const float* __restrict__ pw = params + n * 169;
    const int   stride  = *stride_p;
    const float inv_soi = 1.0f / soi[n];
    const float loc_x   = locs[2*n+0];
    const float loc_y   = locs[2*n+1];
    const float* fbase  = feats + im_inds[n] * (8*HH*WW);

    const float xstep = -(float)stride * inv_soi;

    // ---- MLP over low-res rows, strips of 8 px, packed fp32 pairs ----
    const int nstrips = lcount * STRIPS;
    for (int s = t; s < nstrips; s += NT) {
        const int r  = s / STRIPS;
        const int c0 = (s - r*STRIPS) * 8;
        const int gy = ly0 + r;                     // <= 127 by construction
        const float* frow = fbase + gy*WW + c0;

        const float yrel = (loc_y - (float)(gy*stride + (stride>>1))) * inv_soi;
        const float xr0  = (loc_x - (float)(c0*stride + (stride>>1))) * inv_soi;

        #pragma unroll
        for (int g = 0; g < 2; ++g) {
            f32x4 f[8];
            #pragma unroll
            for (int ch = 0; ch < 8; ++ch)
                f[ch] = *(const f32x4*)(frow + ch*(HH*WW) + g*4);

            f32x2 xp0, xp1;
            xp0.x = fmaf((float)(g*4+0), xstep, xr0);
            xp0.y = fmaf((float)(g*4+1), xstep, xr0);
            xp1.x = fmaf((float)(g*4+2), xstep, xr0);
            xp1.y = fmaf((float)(g*4+3), xstep, xr0);

            // layer 0: 10 -> 8, relu (y-term hoisted per strip)
            f32x2 h0a[8], h0b[8];
            #pragma unroll
            for (int o = 0; o < 8; ++o) {
                const float byo = fmaf(yrel, pw[o*10+1], pw[152+o]);
                const float wxw = pw[o*10+0];
                f32x2 a0 = pkfma(xp0, wxw, splat2(byo));
                f32x2 a1 = pkfma(xp1, wxw, splat2(byo));
                #pragma unroll
                for (int ch = 0; ch < 8; ++ch) {
                    const float w = pw[o*10+2+ch];
                    a0 = pkfma(f[ch].xy, w, a0);
                    a1 = pkfma(f[ch].zw, w, a1);
                }
                h0a[o] = relu2(a0);
                h0b[o] = relu2(a1);
            }

            // layers 1+2 fused
            f32x2 res0 = splat2(pw[168]);
            f32x2 res1 = splat2(pw[168]);
            #pragma unroll
            for (int o = 0; o < 8; ++o) {
                const float b1w = pw[160+o];
                const float w2w = pw[144+o];
                f32x2 a0 = splat2(b1w);
                f32x2 a1 = splat2(b1w);
                #pragma unroll
                for (int c = 0; c < 8; ++c) {
                    const float w = pw[80+o*8+c];
                    a0 = pkfma(h0a[c], w, a0);
                    a1 = pkfma(h0b[c], w, a1);
                }
                res0 = pkfma(relu2(a0), w2w, res0);
                res1 = pkfma(relu2(a1), w2w, res1);
            }

            f32x4 rv; rv.x = res0.x; rv.y = res0.y; rv.z = res1.x; rv.w = res1.y;
            *(f32x4*)&tile[r][c0 + g*4] = rv;       // 16B aligned (784B pitch)
        }
    }

    __syncthreads();

    // ---- bilinear upsample: thread = output column, loop 64 rows ----
    // per-thread x constants computed ONCE
    const float xsf = (float)t * sx;
    int ix0 = (int)xsf; if (ix0 > WW-2) ix0 = WW-2;
    const float wxf = xsf - (float)ix0;

    float* ocol = out + (size_t)n * (HO*WO) + (size_t)oy0 * WO + t;
    #pragma unroll 4
    for (int row = 0; row < OTY; ++row) {
        const int   yo  = oy0 + row;
        const float ysf = (float)yo * sy;
        int iy0 = (int)ysf; if (iy0 > HH-2) iy0 = HH-2;
        const float wy = ysf - (float)iy0;
        const float* r0 = &tile[iy0 - ly0][0] + ix0;
        const float* r1 = r0 + LPAD;
        float a = r0[0], b = r0[1];                 // ds_read2_b32
        float c = r1[0], d = r1[1];
        float va = fmaf(wy, c - a, a);
        float vb = fmaf(wy, d - b, b);
        ocol[row * WO] = fmaf(wxf, vb - va, va);    // 256B/wave coalesced
    }
}

extern "C" void kernel_launch(void* const* d_in, const int* in_sizes, int n_in,
                              void* d_out, int out_size, void* d_ws, size_t ws_size,
                              hipStream_t stream) {
    const float* feats    = (const float*)d_in[0];
    const float* params   = (const float*)d_in[1];
    const float* locs     = (const float*)d_in[2];
    const float* soi      = (const float*)d_in[3];
    const int*   im_inds  = (const int*)d_in[4];
    // d_in[5] = fpn_levels (already folded into sizes_of_interest)
    const int*   stride_p = (const int*)d_in[6];
    float* out = (float*)d_out;

    dim3 grid(HO / OTY, NINST);   // (4, 256) = 1024 blocks
    dim3 block(NT);
    hipLaunchKernelGGL(dynmask_fused, grid, block, 0, stream,
                       feats, params, locs, soi, im_inds, stride_p, out);
}

// Round 5
// 50.615 us; speedup vs baseline: 2.3915x; 2.3915x over previous
//
#include <hip/hip_runtime.h>

typedef float f32x2 __attribute__((ext_vector_type(2)));
typedef float f32x4 __attribute__((ext_vector_type(4)));

#define HH 128
#define WW 192
#define HO 256
#define WO 384
#define NINST 256
#define OTY 16          // output rows per block
#define LTY 10          // low-res rows staged
#define LPAD 196        // tile row pitch in floats (784B, 16B aligned)
#define STRIPS 24       // 192/8 strips per low-res row

static __device__ __forceinline__ f32x2 splat2(float v) { f32x2 r; r.x = v; r.y = v; return r; }

static __device__ __forceinline__ f32x2 pkfma(f32x2 a, float w, f32x2 c) {
#if __has_builtin(__builtin_elementwise_fma)
    return __builtin_elementwise_fma(a, splat2(w), c);
#else
    f32x2 r; r.x = fmaf(a.x, w, c.x); r.y = fmaf(a.y, w, c.y); return r;
#endif
}

static __device__ __forceinline__ f32x2 relu2(f32x2 a) {
#if __has_builtin(__builtin_elementwise_max)
    return __builtin_elementwise_max(a, splat2(0.0f));
#else
    f32x2 r; r.x = fmaxf(a.x, 0.0f); r.y = fmaxf(a.y, 0.0f); return r;
#endif
}

__global__ __launch_bounds__(256) void dynmask_fused(
    const float* __restrict__ feats,    // (2, 8, 128, 192)
    const float* __restrict__ params,   // (256, 169)
    const float* __restrict__ locs,     // (256, 2)  [x, y]
    const float* __restrict__ soi,      // (256,)
    const int*   __restrict__ im_inds,  // (256,)
    const int*   __restrict__ stride_p, // (1,)
    float* __restrict__ out)            // (256, 1, 256, 384)
{
    const int n   = blockIdx.y;
    const int t   = threadIdx.x;
    const int oy0 = blockIdx.x * OTY;

    __shared__ float tile[LTY][LPAD];   // 7840 B

    const float sy = 127.0f / 255.0f;
    const float sx = 191.0f / 383.0f;
    const int ly0 = (int)((float)oy0 * sy);

    // wave-uniform -> SGPRs / s_loads
    const float* __restrict__ pw = params + n * 169;
    const int   stride  = *stride_p;
    const float inv_soi = 1.0f / soi[n];
    const float loc_x   = locs[2*n+0];
    const float loc_y   = locs[2*n+1];
    const float* fbase  = feats + im_inds[n] * (8*HH*WW);
    const float xstep   = -(float)stride * inv_soi;

    // ---- MLP: 240 threads, one 8-px strip each, packed f32x2 math ----
    if (t < LTY * STRIPS) {
        const int r  = (unsigned)t / STRIPS;          // 0..9
        const int c0 = (t - r*STRIPS) * 8;
        int gy = ly0 + r; if (gy > HH-1) gy = HH-1;   // duplicate last row, benign
        const float* frow = fbase + gy*WW + c0;

        const float yrel = (loc_y - (float)(gy*stride + (stride>>1))) * inv_soi;
        const float xr0  = (loc_x - (float)(c0*stride + (stride>>1))) * inv_soi;

        #pragma unroll
        for (int g = 0; g < 2; ++g) {
            f32x4 f[8];
            #pragma unroll
            for (int ch = 0; ch < 8; ++ch)
                f[ch] = *(const f32x4*)(frow + ch*(HH*WW) + g*4);

            f32x2 xp0, xp1;
            xp0.x = fmaf((float)(g*4+0), xstep, xr0);
            xp0.y = fmaf((float)(g*4+1), xstep, xr0);
            xp1.x = fmaf((float)(g*4+2), xstep, xr0);
            xp1.y = fmaf((float)(g*4+3), xstep, xr0);

            f32x2 h0a[8], h0b[8];
            #pragma unroll
            for (int o = 0; o < 8; ++o) {
                const float byo = fmaf(yrel, pw[o*10+1], pw[152+o]);  // y-term hoisted
                const float wxw = pw[o*10+0];
                f32x2 a0 = pkfma(xp0, wxw, splat2(byo));
                f32x2 a1 = pkfma(xp1, wxw, splat2(byo));
                #pragma unroll
                for (int ch = 0; ch < 8; ++ch) {
                    const float w = pw[o*10+2+ch];
                    a0 = pkfma(f[ch].xy, w, a0);
                    a1 = pkfma(f[ch].zw, w, a1);
                }
                h0a[o] = relu2(a0);
                h0b[o] = relu2(a1);
            }

            f32x2 res0 = splat2(pw[168]);
            f32x2 res1 = splat2(pw[168]);
            #pragma unroll
            for (int o = 0; o < 8; ++o) {
                const float b1w = pw[160+o];
                const float w2w = pw[144+o];
                f32x2 a0 = splat2(b1w);
                f32x2 a1 = splat2(b1w);
                #pragma unroll
                for (int c = 0; c < 8; ++c) {
                    const float w = pw[80+o*8+c];
                    a0 = pkfma(h0a[c], w, a0);
                    a1 = pkfma(h0b[c], w, a1);
                }
                res0 = pkfma(relu2(a0), w2w, res0);
                res1 = pkfma(relu2(a1), w2w, res1);
            }

            f32x4 rv; rv.x = res0.x; rv.y = res0.y; rv.z = res1.x; rv.w = res1.y;
            *(f32x4*)&tile[r][c0 + g*4] = rv;
        }
    }

    __syncthreads();

    // ---- upsample: 3 units/thread, unit = (one column, 8 rows) ----
    // x-math once per unit; y-rows reused across the 8-row run (iy0 steps 0/+1,
    // thread-uniform branch); coalesced 4B stores (lanes -> consecutive cols).
    float* obase = out + (size_t)n * (HO*WO);
    #pragma unroll
    for (int k = 0; k < 3; ++k) {
        const int u    = t + k*256;                 // 0..767
        const int wrap = (u >= 384);
        const int col  = wrap ? u - 384 : u;        // 0..383 (wave-uniform select)
        const int r0o  = wrap ? 8 : 0;              // row half: 0..7 or 8..15

        const float xsf = (float)col * sx;
        int ix0 = (int)xsf; if (ix0 > WW-2) ix0 = WW-2;
        const float wx = xsf - (float)ix0;
        const float* tcol = &tile[0][0] + ix0;

        float a, b, c, d;
        int prevIy = -999;
        float* optr = obase + (size_t)(oy0 + r0o) * WO + col;

        for (int rr = 0; rr < 8; ++rr) {
            const int   yo  = oy0 + r0o + rr;
            const float ysf = (float)yo * sy;
            int iy0 = (int)ysf; if (iy0 > HH-2) iy0 = HH-2;
            const float wy = ysf - (float)iy0;

            if (iy0 != prevIy) {                     // thread-uniform branch
                const float* p = tcol + (iy0 - ly0) * LPAD;
                if (iy0 == prevIy + 1) {
                    a = c; b = d;                    // shift: reuse lower row
                    c = p[LPAD]; d = p[LPAD+1];      // one ds_read2
                } else {
                    a = p[0];    b = p[1];
                    c = p[LPAD]; d = p[LPAD+1];
                }
                prevIy = iy0;
            }

            float va = fmaf(wy, c - a, a);
            float vb = fmaf(wy, d - b, b);
            *optr = fmaf(wx, vb - va, va);
            optr += WO;
        }
    }
}

extern "C" void kernel_launch(void* const* d_in, const int* in_sizes, int n_in,
                              void* d_out, int out_size, void* d_ws, size_t ws_size,
                              hipStream_t stream) {
    const float* feats    = (const float*)d_in[0];
    const float* params   = (const float*)d_in[1];
    const float* locs     = (const float*)d_in[2];
    const float* soi      = (const float*)d_in[3];
    const int*   im_inds  = (const int*)d_in[4];
    // d_in[5] = fpn_levels (already folded into sizes_of_interest)
    const int*   stride_p = (const int*)d_in[6];
    float* out = (float*)d_out;

    dim3 grid(HO / OTY, NINST);   // (16, 256) = 4096 blocks
    dim3 block(256);
    hipLaunchKernelGGL(dynmask_fused, grid, block, 0, stream,
                       feats, params, locs, soi, im_inds, stride_p, out);
}